// Round 1
// baseline (1038.530 us; speedup 1.0000x reference)
//
#include <hip/hip_runtime.h>
#include <stdint.h>

typedef unsigned short u16;
typedef __attribute__((ext_vector_type(8))) short s16x8;   // 8 x bf16 (4 VGPRs)
typedef __attribute__((ext_vector_type(4))) float f32x4;

#define DEV static __device__ __forceinline__

#define MFMA16(a, b, c) __builtin_amdgcn_mfma_f32_16x16x32_bf16((a), (b), (c), 0, 0, 0)

// fp32 -> bf16 round-to-nearest-even
DEV u16 f2b(float f) {
  unsigned u = __float_as_uint(f);
  unsigned r = (u + 0x7fffu + ((u >> 16) & 1u)) >> 16;
  return (u16)r;
}

typedef const __attribute__((address_space(1))) unsigned int* as1p;
typedef __attribute__((address_space(3))) unsigned int* as3p;

// async global->LDS, 16B per lane; lds base must be wave-uniform (HW adds lane*16)
DEV void gload16(const void* g, void* l) {
  __builtin_amdgcn_global_load_lds((as1p)(uintptr_t)g, (as3p)(unsigned)(uintptr_t)l, 16, 0, 0);
}

// ---------------------------------------------------------------------------
// prep kernels
// ---------------------------------------------------------------------------
__global__ void conv_x_k(const float* __restrict__ x, u16* __restrict__ xb) {
  const int n8 = 32768 * 1024 / 8;
  int i = blockIdx.x * 256 + threadIdx.x;     // 8 floats per thread
  int stride = gridDim.x * 256;
  for (; i < n8; i += stride) {
    const float4* p = (const float4*)x + (size_t)i * 2;
    float4 a = p[0], c = p[1];
    union { s16x8 v; u16 u[8]; } o;
    o.u[0] = f2b(a.x); o.u[1] = f2b(a.y); o.u[2] = f2b(a.z); o.u[3] = f2b(a.w);
    o.u[4] = f2b(c.x); o.u[5] = f2b(c.y); o.u[6] = f2b(c.z); o.u[7] = f2b(c.w);
    *(s16x8*)(xb + (size_t)i * 8) = o.v;
  }
}

// transpose 1024x1024 f32 -> bf16 B^T layouts for all four weights
__global__ void transp_w_k(const float* __restrict__ Wq, const float* __restrict__ Wk,
                           const float* __restrict__ Wv, const float* __restrict__ Wo,
                           u16* __restrict__ wqkT, u16* __restrict__ wvT, u16* __restrict__ woT) {
  const int z = blockIdx.z;
  const float* src = z == 0 ? Wq : z == 1 ? Wk : z == 2 ? Wv : Wo;
  u16* dst = z == 0 ? wqkT : z == 1 ? (wqkT + 1024 * 1024) : z == 2 ? wvT : woT;
  __shared__ u16 t[64][72];
  const int kb = blockIdx.y * 64, nb = blockIdx.x * 64;
  const int tid = threadIdx.x;
  const int c = tid & 63, r0 = tid >> 6;
  #pragma unroll
  for (int s = 0; s < 16; ++s) {
    int r = r0 * 16 + s;
    t[r][c] = f2b(src[(size_t)(kb + r) * 1024 + nb + c]);
  }
  __syncthreads();
  #pragma unroll
  for (int s = 0; s < 16; ++s) {
    int n = r0 * 16 + s;
    dst[(size_t)(nb + n) * 1024 + kb + c] = t[c][n];   // out[n][k] = in[k][n]
  }
}

// rel_k -> bf16 [240][64] (zero pad t>=225); rel_v -> bf16 transposed [64][256] (zero pad)
__global__ void prep_rel_k(const float* __restrict__ rk, const float* __restrict__ rv,
                           u16* __restrict__ rkb, u16* __restrict__ rvT) {
  int i = blockIdx.x * 256 + threadIdx.x;
  if (i < 240 * 64) {
    int tt = i >> 6, d = i & 63;
    rkb[i] = (tt < 225) ? f2b(rk[tt * 64 + d]) : (u16)0;
  }
  if (i < 64 * 256) {
    int d = i >> 8, tt = i & 255;
    rvT[i] = (tt < 225) ? f2b(rv[tt * 64 + d]) : (u16)0;
  }
}

// ---------------------------------------------------------------------------
// 128x128x(K=1024) bf16 MFMA GEMM, BK=32, 4 waves (2x2), 4x4 16x16x32 frags/wave
// A [M][1024] row-major bf16, BT [N][1024] row-major bf16 (i.e. B transposed)
// EPI 0: QK + fused RMSNorm -> o16a=qn, o16b=kn ([B,H,L,dk] bf16)
// EPI 1: V^T               -> o16a=vT  ([B,H,dk,L] bf16)
// EPI 2: fp32 out [M][1024]
// ---------------------------------------------------------------------------
template <int EPI>
__global__ __launch_bounds__(256, 2)
void gemm_k(const u16* __restrict__ A, const u16* __restrict__ BT,
            u16* __restrict__ o16a, u16* __restrict__ o16b,
            float* __restrict__ oF,
            const float* __restrict__ qsc, const float* __restrict__ ksc) {
  __shared__ u16 smA[2][128 * 32];
  __shared__ u16 smB[2][128 * 32];
  const int tid = threadIdx.x;
  const int w = tid >> 6, l = tid & 63;
  const int lc = l & 15, l4 = l >> 4;
  const int m0 = blockIdx.y * 128, n0 = blockIdx.x * 128;
  const int wm = (w >> 1) * 64, wn = (w & 1) * 64;

  f32x4 acc[4][4];
  #pragma unroll
  for (int i = 0; i < 4; ++i)
    #pragma unroll
    for (int j = 0; j < 4; ++j) acc[i][j] = (f32x4){0.f, 0.f, 0.f, 0.f};

  // staging source mapping (XOR swizzle on byte bits [5:4] by row: x = (row^(row>>2))&3)
  int srcRow[2], srcCol[2];
  #pragma unroll
  for (int s = 0; s < 2; ++s) {
    int p = w * 2048 + s * 1024 + l * 16;           // physical LDS byte
    int row = p >> 6;                                // 64B per row (BK=32 bf16)
    int lb = p ^ (((row ^ (row >> 2)) & 3) << 4);    // logical byte
    srcRow[s] = row;
    srcCol[s] = (lb & 63) >> 1;                      // element offset in k-tile
  }

  auto stage = [&](int buf, int kt) {
    #pragma unroll
    for (int s = 0; s < 2; ++s) {
      int base = w * 2048 + s * 1024;                // wave-uniform LDS byte base
      const u16* ga = A + (size_t)(m0 + srcRow[s]) * 1024 + kt * 32 + srcCol[s];
      gload16(ga, (char*)&smA[buf][0] + base);
      const u16* gb = BT + (size_t)(n0 + srcRow[s]) * 1024 + kt * 32 + srcCol[s];
      gload16(gb, (char*)&smB[buf][0] + base);
    }
  };
  auto fragA = [&](int buf, int mf) -> s16x8 {
    int row = wm + mf * 16 + lc;
    int p = (row << 6) + (l4 << 4);
    p ^= ((row ^ (row >> 2)) & 3) << 4;
    return *(const s16x8*)((const char*)&smA[buf][0] + p);
  };
  auto fragB = [&](int buf, int nf) -> s16x8 {
    int row = wn + nf * 16 + lc;
    int p = (row << 6) + (l4 << 4);
    p ^= ((row ^ (row >> 2)) & 3) << 4;
    return *(const s16x8*)((const char*)&smB[buf][0] + p);
  };

  stage(0, 0);
  __syncthreads();
  #pragma unroll 2
  for (int kt = 0; kt < 32; ++kt) {
    int cur = kt & 1;
    if (kt + 1 < 32) stage(cur ^ 1, kt + 1);
    s16x8 af[4], bf[4];
    #pragma unroll
    for (int i = 0; i < 4; ++i) { af[i] = fragA(cur, i); bf[i] = fragB(cur, i); }
    #pragma unroll
    for (int mf = 0; mf < 4; ++mf)
      #pragma unroll
      for (int nf = 0; nf < 4; ++nf)
        acc[mf][nf] = MFMA16(af[mf], bf[nf], acc[mf][nf]);
    __syncthreads();
  }

  // epilogue; C layout: col = lane&15 (+16*nf), row = (lane>>4)*4 + reg (+16*mf)
  if constexpr (EPI == 2) {
    #pragma unroll
    for (int mf = 0; mf < 4; ++mf)
      #pragma unroll
      for (int r = 0; r < 4; ++r) {
        int gm = m0 + wm + mf * 16 + l4 * 4 + r;
        #pragma unroll
        for (int nf = 0; nf < 4; ++nf) {
          int gn = n0 + wn + nf * 16 + lc;
          oF[(size_t)gm * 1024 + gn] = acc[mf][nf][r];
        }
      }
  } else if constexpr (EPI == 1) {
    #pragma unroll
    for (int mf = 0; mf < 4; ++mf)
      #pragma unroll
      for (int r = 0; r < 4; ++r) {
        int gm = m0 + wm + mf * 16 + l4 * 4 + r;       // h*64+d
        #pragma unroll
        for (int nf = 0; nf < 4; ++nf) {
          int gn = n0 + wn + nf * 16 + lc;             // b*64+l
          size_t addr = (((size_t)(gn >> 6) * 16 + (gm >> 6)) * 64 + (gm & 63)) * 64 + (gn & 63);
          o16a[addr] = f2b(acc[mf][nf][r]);
        }
      }
  } else {
    int nw0 = n0 + wn;                                  // wave = exactly one head (64 cols)
    bool isq = nw0 < 1024;
    const float* sc = isq ? qsc : ksc;
    u16* dst = isq ? o16a : o16b;
    int h = (nw0 & 1023) >> 6;
    float scv[4];
    #pragma unroll
    for (int nf = 0; nf < 4; ++nf) scv[nf] = sc[nf * 16 + lc];
    #pragma unroll
    for (int mf = 0; mf < 4; ++mf)
      #pragma unroll
      for (int r = 0; r < 4; ++r) {
        float ss = 0.f;
        #pragma unroll
        for (int nf = 0; nf < 4; ++nf) ss += acc[mf][nf][r] * acc[mf][nf][r];
        #pragma unroll
        for (int mask = 1; mask < 16; mask <<= 1) ss += __shfl_xor(ss, mask, 64);
        float rinv = rsqrtf(ss * 0.015625f + 1e-6f);    // 1/sqrt(mean+eps)
        int gm = m0 + wm + mf * 16 + l4 * 4 + r;
        size_t base = (((size_t)(gm >> 6) * 16 + h) * 64 + (gm & 63)) * 64;
        #pragma unroll
        for (int nf = 0; nf < 4; ++nf)
          dst[base + nf * 16 + lc] = f2b(acc[mf][nf][r] * rinv * scv[nf]);
      }
  }
}

// ---------------------------------------------------------------------------
// attention: one block (4 waves) per (b,h); wave w owns query rows [16w,16w+16)
// ---------------------------------------------------------------------------
// Rw (f32 [64][256]) is used first for R = q @ rel_k^T scores, then reused as
// the scatter-accumulated W[i,t]. 16B-granular XOR swizzle kills the 16-way
// bank conflict on the stride-1KB fragment reads.
DEV int rwIdx(int row, int col) {
  int c16 = (col >> 2) ^ (row & 7);
  return row * 256 + (c16 << 2) + (col & 3);
}

__global__ __launch_bounds__(256, 2)
void attn_k(const u16* __restrict__ qn, const u16* __restrict__ kn,
            const u16* __restrict__ vT, const u16* __restrict__ rkb,
            const u16* __restrict__ rvT, const int* __restrict__ ridx,
            u16* __restrict__ ao) {
  __shared__ float Rw[64 * 256];
  __shared__ u16 Pl[64 * 72];
  const int bid = blockIdx.x;
  const int b = bid >> 4, h = bid & 15;
  const int tid = threadIdx.x;
  const int w = tid >> 6, l = tid & 63;
  const int lc = l & 15, l4 = l >> 4;
  const int i0 = w * 16;
  const size_t hb = (size_t)(b * 16 + h) * 4096;
  const u16* qh = qn + hb;
  const u16* kh = kn + hb;
  const u16* vh = vT + hb;

  // P1: content = Q @ K^T (frags straight from global; tiles are L1-resident)
  s16x8 aq0 = *(const s16x8*)(qh + (i0 + lc) * 64 + l4 * 8);
  s16x8 aq1 = *(const s16x8*)(qh + (i0 + lc) * 64 + 32 + l4 * 8);
  f32x4 accC[4];
  #pragma unroll
  for (int nf = 0; nf < 4; ++nf) accC[nf] = (f32x4){0.f, 0.f, 0.f, 0.f};
  #pragma unroll
  for (int nf = 0; nf < 4; ++nf) {
    s16x8 b0 = *(const s16x8*)(kh + (nf * 16 + lc) * 64 + l4 * 8);
    s16x8 b1 = *(const s16x8*)(kh + (nf * 16 + lc) * 64 + 32 + l4 * 8);
    accC[nf] = MFMA16(aq0, b0, accC[nf]);
    accC[nf] = MFMA16(aq1, b1, accC[nf]);
  }
  // P2: R[i,t] = q_i . rel_k[t], t in [0,240)
  #pragma unroll
  for (int nf = 0; nf < 15; ++nf) {
    f32x4 rr = (f32x4){0.f, 0.f, 0.f, 0.f};
    s16x8 b0 = *(const s16x8*)(rkb + (nf * 16 + lc) * 64 + l4 * 8);
    s16x8 b1 = *(const s16x8*)(rkb + (nf * 16 + lc) * 64 + 32 + l4 * 8);
    rr = MFMA16(aq0, b0, rr);
    rr = MFMA16(aq1, b1, rr);
    int t = nf * 16 + lc;
    #pragma unroll
    for (int q = 0; q < 4; ++q) Rw[rwIdx(i0 + l4 * 4 + q, t)] = rr[q];
  }
  __syncthreads();
  // P3: gather rel, scores, 16-lane-group softmax, stash P (bf16) for PV
  float ev[4][4];
  int ts[4][4];
  float linv[4];
  #pragma unroll
  for (int q = 0; q < 4; ++q) {
    int row = i0 + l4 * 4 + q;
    float mx = -1e30f;
    #pragma unroll
    for (int nf = 0; nf < 4; ++nf) {
      int j = nf * 16 + lc;
      int t = ridx[row * 64 + j];
      ts[nf][q] = t;
      float s = (accC[nf][q] + Rw[rwIdx(row, t)]) * 0.125f;
      ev[nf][q] = s;
      mx = fmaxf(mx, s);
    }
    #pragma unroll
    for (int mask = 1; mask < 16; mask <<= 1) mx = fmaxf(mx, __shfl_xor(mx, mask, 64));
    float sum = 0.f;
    #pragma unroll
    for (int nf = 0; nf < 4; ++nf) { float e = __expf(ev[nf][q] - mx); ev[nf][q] = e; sum += e; }
    #pragma unroll
    for (int mask = 1; mask < 16; mask <<= 1) sum += __shfl_xor(sum, mask, 64);
    linv[q] = 1.f / sum;
    #pragma unroll
    for (int nf = 0; nf < 4; ++nf) Pl[row * 72 + nf * 16 + lc] = f2b(ev[nf][q]);
  }
  __syncthreads();
  // P4: zero W
  {
    f32x4 z = (f32x4){0.f, 0.f, 0.f, 0.f};
    for (int c = tid; c < 64 * 256 / 4; c += 256) ((f32x4*)Rw)[c] = z;
  }
  __syncthreads();
  // P5: scatter unnormalized probs: W[i, idx[i,j]] += E[i,j]
  #pragma unroll
  for (int q = 0; q < 4; ++q)
    #pragma unroll
    for (int nf = 0; nf < 4; ++nf)
      atomicAdd(&Rw[rwIdx(i0 + l4 * 4 + q, ts[nf][q])], ev[nf][q]);
  __syncthreads();
  // P6: out = E @ V  +  W @ rel_v   (normalize by 1/sum at the end)
  f32x4 accO[4];
  #pragma unroll
  for (int nf = 0; nf < 4; ++nf) accO[nf] = (f32x4){0.f, 0.f, 0.f, 0.f};
  s16x8 pa0 = *(const s16x8*)(&Pl[(i0 + lc) * 72 + l4 * 8]);
  s16x8 pa1 = *(const s16x8*)(&Pl[(i0 + lc) * 72 + 32 + l4 * 8]);
  #pragma unroll
  for (int nf = 0; nf < 4; ++nf) {
    s16x8 b0 = *(const s16x8*)(vh + (nf * 16 + lc) * 64 + l4 * 8);
    s16x8 b1 = *(const s16x8*)(vh + (nf * 16 + lc) * 64 + 32 + l4 * 8);
    accO[nf] = MFMA16(pa0, b0, accO[nf]);
    accO[nf] = MFMA16(pa1, b1, accO[nf]);
  }
  #pragma unroll
  for (int ks = 0; ks < 8; ++ks) {
    int row = i0 + lc;
    int c16 = ks * 8 + l4 * 2;
    f32x4 w0 = *(const f32x4*)&Rw[row * 256 + ((c16 ^ (row & 7)) << 2)];
    f32x4 w1 = *(const f32x4*)&Rw[row * 256 + (((c16 + 1) ^ (row & 7)) << 2)];
    union { s16x8 v; u16 u[8]; } wa;
    #pragma unroll
    for (int j = 0; j < 4; ++j) { wa.u[j] = f2b(w0[j]); wa.u[4 + j] = f2b(w1[j]); }
    #pragma unroll
    for (int nf = 0; nf < 4; ++nf) {
      s16x8 rb = *(const s16x8*)(rvT + (nf * 16 + lc) * 256 + ks * 32 + l4 * 8);
      accO[nf] = MFMA16(wa.v, rb, accO[nf]);
    }
  }
  // P7: write [B,L,H*dk] bf16
  #pragma unroll
  for (int q = 0; q < 4; ++q) {
    int row = i0 + l4 * 4 + q;
    #pragma unroll
    for (int nf = 0; nf < 4; ++nf) {
      int d = nf * 16 + lc;
      ao[((size_t)(b * 64 + row)) * 1024 + h * 64 + d] = f2b(accO[nf][q] * linv[q]);
    }
  }
}

// ---------------------------------------------------------------------------
extern "C" void kernel_launch(void* const* d_in, const int* in_sizes, int n_in,
                              void* d_out, int out_size, void* d_ws, size_t ws_size,
                              hipStream_t stream) {
  (void)in_sizes; (void)n_in; (void)out_size; (void)ws_size;
  const float* x  = (const float*)d_in[0];
  const int* ridx = (const int*)d_in[1];   // harness delivers integer inputs as int32
  const float* Wq = (const float*)d_in[2];
  const float* Wk = (const float*)d_in[3];
  const float* Wv = (const float*)d_in[4];
  const float* Wo = (const float*)d_in[5];
  const float* qs = (const float*)d_in[6];
  const float* ks = (const float*)d_in[7];
  const float* rk = (const float*)d_in[8];
  const float* rv = (const float*)d_in[9];
  float* out = (float*)d_out;

  char* ws = (char*)d_ws;
  const size_t SZ = 32768ull * 1024 * 2;            // 64 MiB (bf16 activation)
  u16* xb   = (u16*)(ws);                           // x bf16; later reused as attn out
  u16* qn   = (u16*)(ws + SZ);                      // Q rmsnorm'd [B,H,L,dk]
  u16* kn   = (u16*)(ws + 2 * SZ);                  // K rmsnorm'd [B,H,L,dk]
  u16* vT   = (u16*)(ws + 3 * SZ);                  // V^T [B,H,dk,L]
  u16* wqkT = (u16*)(ws + 4 * SZ);                  // [2048][1024]
  u16* wvT  = (u16*)(ws + 4 * SZ + 4194304);        // [1024][1024]
  u16* woT  = (u16*)(ws + 4 * SZ + 6291456);        // [1024][1024]
  u16* rkb  = (u16*)(ws + 4 * SZ + 8388608);        // [240][64]
  u16* rvTb = (u16*)(ws + 4 * SZ + 8388608 + 30720);// [64][256]

  conv_x_k<<<2048, 256, 0, stream>>>(x, xb);
  transp_w_k<<<dim3(16, 16, 4), 256, 0, stream>>>(Wq, Wk, Wv, Wo, wqkT, wvT, woT);
  prep_rel_k<<<64, 256, 0, stream>>>(rk, rv, rkb, rvTb);
  // Q,K projection + fused RMSNorm
  gemm_k<0><<<dim3(16, 256), 256, 0, stream>>>(xb, wqkT, qn, kn, nullptr, qs, ks);
  // V^T = Wv^T @ x^T
  gemm_k<1><<<dim3(256, 8), 256, 0, stream>>>(wvT, xb, vT, nullptr, nullptr, nullptr, nullptr);
  // attention (overwrites xb with [B,L,D] bf16 attention output)
  attn_k<<<8192, 256, 0, stream>>>(qn, kn, vT, rkb, rvTb, ridx, xb);
  // final projection -> fp32 out
  gemm_k<2><<<dim3(8, 256), 256, 0, stream>>>(xb, woT, nullptr, nullptr, out, nullptr, nullptr);
}

// Round 2
// 965.993 us; speedup vs baseline: 1.0751x; 1.0751x over previous
//
#include <hip/hip_runtime.h>
#include <stdint.h>

typedef unsigned short u16;
typedef __attribute__((ext_vector_type(8))) short s16x8;   // 8 x bf16 (4 VGPRs)
typedef __attribute__((ext_vector_type(4))) float f32x4;

#define DEV static __device__ __forceinline__

#define MFMA16(a, b, c) __builtin_amdgcn_mfma_f32_16x16x32_bf16((a), (b), (c), 0, 0, 0)

// fp32 -> bf16 round-to-nearest-even
DEV u16 f2b(float f) {
  unsigned u = __float_as_uint(f);
  unsigned r = (u + 0x7fffu + ((u >> 16) & 1u)) >> 16;
  return (u16)r;
}
DEV float b2f(u16 u) { return __uint_as_float(((unsigned)u) << 16); }

typedef const __attribute__((address_space(1))) unsigned int* as1p;
typedef __attribute__((address_space(3))) unsigned int* as3p;

// async global->LDS, 16B per lane; lds base must be wave-uniform (HW adds lane*16)
DEV void gload16(const void* g, void* l) {
  __builtin_amdgcn_global_load_lds((as1p)(uintptr_t)g, (as3p)(unsigned)(uintptr_t)l, 16, 0, 0);
}

// packed bf16x2 LDS atomic add (ds_pk_add_bf16)
DEV void ldsPkAddBf16(void* ldsPtr, unsigned packed) {
  unsigned addr = (unsigned)(uintptr_t)ldsPtr;
  asm volatile("ds_pk_add_bf16 %0, %1" : : "v"(addr), "v"(packed) : "memory");
}

// ---------------------------------------------------------------------------
// prep kernels
// ---------------------------------------------------------------------------
__global__ void conv_x_k(const float* __restrict__ x, u16* __restrict__ xb) {
  const int n8 = 32768 * 1024 / 8;
  int i = blockIdx.x * 256 + threadIdx.x;     // 8 floats per thread
  int stride = gridDim.x * 256;
  for (; i < n8; i += stride) {
    const float4* p = (const float4*)x + (size_t)i * 2;
    float4 a = p[0], c = p[1];
    union { s16x8 v; u16 u[8]; } o;
    o.u[0] = f2b(a.x); o.u[1] = f2b(a.y); o.u[2] = f2b(a.z); o.u[3] = f2b(a.w);
    o.u[4] = f2b(c.x); o.u[5] = f2b(c.y); o.u[6] = f2b(c.z); o.u[7] = f2b(c.w);
    *(s16x8*)(xb + (size_t)i * 8) = o.v;
  }
}

// transpose 1024x1024 f32 -> bf16 B^T layouts for all four weights
__global__ void transp_w_k(const float* __restrict__ Wq, const float* __restrict__ Wk,
                           const float* __restrict__ Wv, const float* __restrict__ Wo,
                           u16* __restrict__ wqkT, u16* __restrict__ wvT, u16* __restrict__ woT) {
  const int z = blockIdx.z;
  const float* src = z == 0 ? Wq : z == 1 ? Wk : z == 2 ? Wv : Wo;
  u16* dst = z == 0 ? wqkT : z == 1 ? (wqkT + 1024 * 1024) : z == 2 ? wvT : woT;
  __shared__ u16 t[64][72];
  const int kb = blockIdx.y * 64, nb = blockIdx.x * 64;
  const int tid = threadIdx.x;
  const int c = tid & 63, r0 = tid >> 6;
  #pragma unroll
  for (int s = 0; s < 16; ++s) {
    int r = r0 * 16 + s;
    t[r][c] = f2b(src[(size_t)(kb + r) * 1024 + nb + c]);
  }
  __syncthreads();
  #pragma unroll
  for (int s = 0; s < 16; ++s) {
    int n = r0 * 16 + s;
    dst[(size_t)(nb + n) * 1024 + kb + c] = t[c][n];   // out[n][k] = in[k][n]
  }
}

// rel_k -> bf16 [240][64] (zero pad t>=225); rel_v -> bf16 transposed [64][256] (zero pad)
__global__ void prep_rel_k(const float* __restrict__ rk, const float* __restrict__ rv,
                           u16* __restrict__ rkb, u16* __restrict__ rvT) {
  int i = blockIdx.x * 256 + threadIdx.x;
  if (i < 240 * 64) {
    int tt = i >> 6, d = i & 63;
    rkb[i] = (tt < 225) ? f2b(rk[tt * 64 + d]) : (u16)0;
  }
  if (i < 64 * 256) {
    int d = i >> 8, tt = i & 255;
    rvT[i] = (tt < 225) ? f2b(rv[tt * 64 + d]) : (u16)0;
  }
}

// ---------------------------------------------------------------------------
// 128x128x(K=1024) bf16 MFMA GEMM, BK=32, 4 waves (2x2), 4x4 16x16x32 frags/wave
// ---------------------------------------------------------------------------
template <int EPI>
__global__ __launch_bounds__(256, 2)
void gemm_k(const u16* __restrict__ A, const u16* __restrict__ BT,
            u16* __restrict__ o16a, u16* __restrict__ o16b,
            float* __restrict__ oF,
            const float* __restrict__ qsc, const float* __restrict__ ksc) {
  __shared__ u16 smA[2][128 * 32];
  __shared__ u16 smB[2][128 * 32];
  const int tid = threadIdx.x;
  const int w = tid >> 6, l = tid & 63;
  const int lc = l & 15, l4 = l >> 4;
  // bijective XCD swizzle (nwg % 8 == 0 for all our grids)
  const int nwg = gridDim.x * gridDim.y;
  const int orig = blockIdx.y * gridDim.x + blockIdx.x;
  const int wg = ((orig & 7) * (nwg >> 3)) + (orig >> 3);
  const int bx = wg % gridDim.x, by = wg / gridDim.x;
  const int m0 = by * 128, n0 = bx * 128;
  const int wm = (w >> 1) * 64, wn = (w & 1) * 64;

  f32x4 acc[4][4];
  #pragma unroll
  for (int i = 0; i < 4; ++i)
    #pragma unroll
    for (int j = 0; j < 4; ++j) acc[i][j] = (f32x4){0.f, 0.f, 0.f, 0.f};

  // staging source mapping (XOR swizzle on byte bits [5:4] by row: x = (row^(row>>2))&3)
  int srcRow[2], srcCol[2];
  #pragma unroll
  for (int s = 0; s < 2; ++s) {
    int p = w * 2048 + s * 1024 + l * 16;           // physical LDS byte
    int row = p >> 6;                                // 64B per row (BK=32 bf16)
    int lb = p ^ (((row ^ (row >> 2)) & 3) << 4);    // logical byte
    srcRow[s] = row;
    srcCol[s] = (lb & 63) >> 1;                      // element offset in k-tile
  }

  auto stage = [&](int buf, int kt) {
    #pragma unroll
    for (int s = 0; s < 2; ++s) {
      int base = w * 2048 + s * 1024;                // wave-uniform LDS byte base
      const u16* ga = A + (size_t)(m0 + srcRow[s]) * 1024 + kt * 32 + srcCol[s];
      gload16(ga, (char*)&smA[buf][0] + base);
      const u16* gb = BT + (size_t)(n0 + srcRow[s]) * 1024 + kt * 32 + srcCol[s];
      gload16(gb, (char*)&smB[buf][0] + base);
    }
  };
  auto fragA = [&](int buf, int mf) -> s16x8 {
    int row = wm + mf * 16 + lc;
    int p = (row << 6) + (l4 << 4);
    p ^= ((row ^ (row >> 2)) & 3) << 4;
    return *(const s16x8*)((const char*)&smA[buf][0] + p);
  };
  auto fragB = [&](int buf, int nf) -> s16x8 {
    int row = wn + nf * 16 + lc;
    int p = (row << 6) + (l4 << 4);
    p ^= ((row ^ (row >> 2)) & 3) << 4;
    return *(const s16x8*)((const char*)&smB[buf][0] + p);
  };

  stage(0, 0);
  __syncthreads();
  #pragma unroll 2
  for (int kt = 0; kt < 32; ++kt) {
    int cur = kt & 1;
    if (kt + 1 < 32) stage(cur ^ 1, kt + 1);
    s16x8 af[4], bf[4];
    #pragma unroll
    for (int i = 0; i < 4; ++i) { af[i] = fragA(cur, i); bf[i] = fragB(cur, i); }
    #pragma unroll
    for (int mf = 0; mf < 4; ++mf)
      #pragma unroll
      for (int nf = 0; nf < 4; ++nf)
        acc[mf][nf] = MFMA16(af[mf], bf[nf], acc[mf][nf]);
    __syncthreads();
  }

  // epilogue; C layout: col = lane&15 (+16*nf), row = (lane>>4)*4 + reg (+16*mf)
  if constexpr (EPI == 2) {
    #pragma unroll
    for (int mf = 0; mf < 4; ++mf)
      #pragma unroll
      for (int r = 0; r < 4; ++r) {
        int gm = m0 + wm + mf * 16 + l4 * 4 + r;
        #pragma unroll
        for (int nf = 0; nf < 4; ++nf) {
          int gn = n0 + wn + nf * 16 + lc;
          oF[(size_t)gm * 1024 + gn] = acc[mf][nf][r];
        }
      }
  } else if constexpr (EPI == 1) {
    #pragma unroll
    for (int mf = 0; mf < 4; ++mf)
      #pragma unroll
      for (int r = 0; r < 4; ++r) {
        int gm = m0 + wm + mf * 16 + l4 * 4 + r;       // h*64+d
        #pragma unroll
        for (int nf = 0; nf < 4; ++nf) {
          int gn = n0 + wn + nf * 16 + lc;             // b*64+l
          size_t addr = (((size_t)(gn >> 6) * 16 + (gm >> 6)) * 64 + (gm & 63)) * 64 + (gn & 63);
          o16a[addr] = f2b(acc[mf][nf][r]);
        }
      }
  } else {
    int nw0 = n0 + wn;                                  // wave = exactly one head (64 cols)
    bool isq = nw0 < 1024;
    const float* sc = isq ? qsc : ksc;
    u16* dst = isq ? o16a : o16b;
    int h = (nw0 & 1023) >> 6;
    float scv[4];
    #pragma unroll
    for (int nf = 0; nf < 4; ++nf) scv[nf] = sc[nf * 16 + lc];
    #pragma unroll
    for (int mf = 0; mf < 4; ++mf)
      #pragma unroll
      for (int r = 0; r < 4; ++r) {
        float ss = 0.f;
        #pragma unroll
        for (int nf = 0; nf < 4; ++nf) ss += acc[mf][nf][r] * acc[mf][nf][r];
        #pragma unroll
        for (int mask = 1; mask < 16; mask <<= 1) ss += __shfl_xor(ss, mask, 64);
        float rinv = rsqrtf(ss * 0.015625f + 1e-6f);    // 1/sqrt(mean+eps)
        int gm = m0 + wm + mf * 16 + l4 * 4 + r;
        size_t base = (((size_t)(gm >> 6) * 16 + h) * 64 + (gm & 63)) * 64;
        #pragma unroll
        for (int nf = 0; nf < 4; ++nf)
          dst[base + nf * 16 + lc] = f2b(acc[mf][nf][r] * rinv * scv[nf]);
      }
  }
}

// ---------------------------------------------------------------------------
// attention v2: one block (4 waves) per (b,h); wave w owns query rows [16w,16w+16)
// LDS: RW bf16 [64][256] swizzled (R-table, then scatter-W) + Pl bf16 [64][72]
// ---------------------------------------------------------------------------
// swizzled byte address of bf16 element (row, t): 16B slots XORed by row&7
DEV int rwByte(int row, int t) {
  return row * 512 + ((((t >> 3) ^ (row & 7)) << 4)) + ((t & 7) * 2);
}

__global__ __launch_bounds__(256, 3)
void attn_k(const u16* __restrict__ qn, const u16* __restrict__ kn,
            const u16* __restrict__ vT, const u16* __restrict__ rkb,
            const u16* __restrict__ rvT, const int* __restrict__ ridx,
            u16* __restrict__ ao) {
  __shared__ u16 RW[64 * 256];   // 32 KB
  __shared__ u16 Pl[64 * 72];    // 9.2 KB
  const int bid = blockIdx.x;
  const int b = bid >> 4, h = bid & 15;
  const int tid = threadIdx.x;
  const int w = tid >> 6, l = tid & 63;
  const int lc = l & 15, l4 = l >> 4;
  const int i0 = w * 16;
  const size_t hb = (size_t)(b * 16 + h) * 4096;
  const u16* qh = qn + hb;
  const u16* kh = kn + hb;
  const u16* vh = vT + hb;

  // ---- early prefetch: ridx, q, k, v all issued up front (latency hidden)
  int ts[4][4];
  #pragma unroll
  for (int q = 0; q < 4; ++q) {
    int row = i0 + l4 * 4 + q;
    #pragma unroll
    for (int nf = 0; nf < 4; ++nf) ts[nf][q] = ridx[row * 64 + nf * 16 + lc];
  }
  s16x8 aq0 = *(const s16x8*)(qh + (i0 + lc) * 64 + l4 * 8);
  s16x8 aq1 = *(const s16x8*)(qh + (i0 + lc) * 64 + 32 + l4 * 8);
  s16x8 kb0[4], kb1[4], vb0[4], vb1[4];
  #pragma unroll
  for (int nf = 0; nf < 4; ++nf) {
    kb0[nf] = *(const s16x8*)(kh + (nf * 16 + lc) * 64 + l4 * 8);
    kb1[nf] = *(const s16x8*)(kh + (nf * 16 + lc) * 64 + 32 + l4 * 8);
    vb0[nf] = *(const s16x8*)(vh + (nf * 16 + lc) * 64 + l4 * 8);
    vb1[nf] = *(const s16x8*)(vh + (nf * 16 + lc) * 64 + 32 + l4 * 8);
  }

  // P1: content = Q @ K^T
  f32x4 accC[4];
  #pragma unroll
  for (int nf = 0; nf < 4; ++nf) accC[nf] = (f32x4){0.f, 0.f, 0.f, 0.f};
  #pragma unroll
  for (int nf = 0; nf < 4; ++nf) {
    accC[nf] = MFMA16(aq0, kb0[nf], accC[nf]);
    accC[nf] = MFMA16(aq1, kb1[nf], accC[nf]);
  }

  // P2: R[i,t] = q_i . rel_k[t] -> RW (bf16, swizzled). 3 chunks of 5 tiles.
  #pragma unroll
  for (int c = 0; c < 3; ++c) {
    s16x8 rb0[5], rb1[5];
    #pragma unroll
    for (int u = 0; u < 5; ++u) {
      int t0 = (c * 5 + u) * 16;
      rb0[u] = *(const s16x8*)(rkb + (t0 + lc) * 64 + l4 * 8);
      rb1[u] = *(const s16x8*)(rkb + (t0 + lc) * 64 + 32 + l4 * 8);
    }
    #pragma unroll
    for (int u = 0; u < 5; ++u) {
      f32x4 rr = (f32x4){0.f, 0.f, 0.f, 0.f};
      rr = MFMA16(aq0, rb0[u], rr);
      rr = MFMA16(aq1, rb1[u], rr);
      int t = (c * 5 + u) * 16 + lc;
      #pragma unroll
      for (int q = 0; q < 4; ++q) {
        int row = i0 + l4 * 4 + q;
        RW[rwByte(row, t) >> 1] = f2b(rr[q]);
      }
    }
  }
  __syncthreads();                               // A: R visible

  // P3: gather rel, scores, 16-lane-group softmax; stash P (bf16)
  float ev[4][4];
  float linv[4];
  #pragma unroll
  for (int q = 0; q < 4; ++q) {
    int row = i0 + l4 * 4 + q;
    float mx = -1e30f;
    #pragma unroll
    for (int nf = 0; nf < 4; ++nf) {
      float r = b2f(RW[rwByte(row, ts[nf][q]) >> 1]);
      float s = (accC[nf][q] + r) * 0.125f;
      ev[nf][q] = s;
      mx = fmaxf(mx, s);
    }
    #pragma unroll
    for (int mask = 1; mask < 16; mask <<= 1) mx = fmaxf(mx, __shfl_xor(mx, mask, 64));
    float sum = 0.f;
    #pragma unroll
    for (int nf = 0; nf < 4; ++nf) { float e = __expf(ev[nf][q] - mx); ev[nf][q] = e; sum += e; }
    #pragma unroll
    for (int mask = 1; mask < 16; mask <<= 1) sum += __shfl_xor(sum, mask, 64);
    linv[q] = 1.f / sum;
    #pragma unroll
    for (int nf = 0; nf < 4; ++nf) Pl[row * 72 + nf * 16 + lc] = f2b(ev[nf][q]);
  }
  __syncthreads();                               // B: R reads done; Pl visible

  // P4: PV MFMAs (v already in regs) interleaved with zeroing W
  f32x4 accO[4];
  #pragma unroll
  for (int nf = 0; nf < 4; ++nf) accO[nf] = (f32x4){0.f, 0.f, 0.f, 0.f};
  s16x8 pa0 = *(const s16x8*)(&Pl[(i0 + lc) * 72 + l4 * 8]);
  s16x8 pa1 = *(const s16x8*)(&Pl[(i0 + lc) * 72 + 32 + l4 * 8]);
  {
    s16x8 z;
    #pragma unroll
    for (int j = 0; j < 8; ++j) z[j] = 0;
    #pragma unroll
    for (int zz = 0; zz < 8; ++zz) ((s16x8*)RW)[zz * 256 + tid] = z;
  }
  #pragma unroll
  for (int nf = 0; nf < 4; ++nf) {
    accO[nf] = MFMA16(pa0, vb0[nf], accO[nf]);
    accO[nf] = MFMA16(pa1, vb1[nf], accO[nf]);
  }
  __syncthreads();                               // C: W zeroed

  // P5: scatter unnormalized probs via packed-bf16 LDS atomic
  #pragma unroll
  for (int q = 0; q < 4; ++q)
    #pragma unroll
    for (int nf = 0; nf < 4; ++nf) {
      int row = i0 + l4 * 4 + q;
      int t = ts[nf][q];
      int byte = row * 512 + ((((t >> 3) ^ (row & 7)) << 4)) + ((t & 6) * 2);
      unsigned pk = ((unsigned)f2b(ev[nf][q])) << ((t & 1) * 16);
      ldsPkAddBf16((char*)RW + byte, pk);
    }
  asm volatile("s_waitcnt lgkmcnt(0)" ::: "memory");
  __syncthreads();                               // D: W complete

  // P6: accO += W @ rel_v  (W A-frags from swizzled LDS; rvT B-frags from global)
  #pragma unroll
  for (int kc = 0; kc < 4; ++kc) {               // 2 k-steps per chunk
    s16x8 rb[2][4], wa[2];
    #pragma unroll
    for (int s = 0; s < 2; ++s) {
      int ks = kc * 2 + s;
      int row = i0 + lc;
      wa[s] = *(const s16x8*)((const char*)RW + row * 512 + ((((ks * 4 + l4) ^ (row & 7))) << 4));
      #pragma unroll
      for (int nf = 0; nf < 4; ++nf)
        rb[s][nf] = *(const s16x8*)(rvT + (nf * 16 + lc) * 256 + ks * 32 + l4 * 8);
    }
    #pragma unroll
    for (int s = 0; s < 2; ++s)
      #pragma unroll
      for (int nf = 0; nf < 4; ++nf)
        accO[nf] = MFMA16(wa[s], rb[s][nf], accO[nf]);
  }

  // P7: write [B,L,H*dk] bf16
  #pragma unroll
  for (int q = 0; q < 4; ++q) {
    int row = i0 + l4 * 4 + q;
    #pragma unroll
    for (int nf = 0; nf < 4; ++nf) {
      int d = nf * 16 + lc;
      ao[((size_t)(b * 64 + row)) * 1024 + h * 64 + d] = f2b(accO[nf][q] * linv[q]);
    }
  }
}

// ---------------------------------------------------------------------------
extern "C" void kernel_launch(void* const* d_in, const int* in_sizes, int n_in,
                              void* d_out, int out_size, void* d_ws, size_t ws_size,
                              hipStream_t stream) {
  (void)in_sizes; (void)n_in; (void)out_size; (void)ws_size;
  const float* x  = (const float*)d_in[0];
  const int* ridx = (const int*)d_in[1];   // harness delivers integer inputs as int32
  const float* Wq = (const float*)d_in[2];
  const float* Wk = (const float*)d_in[3];
  const float* Wv = (const float*)d_in[4];
  const float* Wo = (const float*)d_in[5];
  const float* qs = (const float*)d_in[6];
  const float* ks = (const float*)d_in[7];
  const float* rk = (const float*)d_in[8];
  const float* rv = (const float*)d_in[9];
  float* out = (float*)d_out;

  char* ws = (char*)d_ws;
  const size_t SZ = 32768ull * 1024 * 2;            // 64 MiB (bf16 activation)
  u16* xb   = (u16*)(ws);                           // x bf16; later reused as attn out
  u16* qn   = (u16*)(ws + SZ);                      // Q rmsnorm'd [B,H,L,dk]
  u16* kn   = (u16*)(ws + 2 * SZ);                  // K rmsnorm'd [B,H,L,dk]
  u16* vT   = (u16*)(ws + 3 * SZ);                  // V^T [B,H,dk,L]
  u16* wqkT = (u16*)(ws + 4 * SZ);                  // [2048][1024]
  u16* wvT  = (u16*)(ws + 4 * SZ + 4194304);        // [1024][1024]
  u16* woT  = (u16*)(ws + 4 * SZ + 6291456);        // [1024][1024]
  u16* rkb  = (u16*)(ws + 4 * SZ + 8388608);        // [240][64]
  u16* rvTb = (u16*)(ws + 4 * SZ + 8388608 + 30720);// [64][256]

  conv_x_k<<<2048, 256, 0, stream>>>(x, xb);
  transp_w_k<<<dim3(16, 16, 4), 256, 0, stream>>>(Wq, Wk, Wv, Wo, wqkT, wvT, woT);
  prep_rel_k<<<64, 256, 0, stream>>>(rk, rv, rkb, rvTb);
  // Q,K projection + fused RMSNorm
  gemm_k<0><<<dim3(16, 256), 256, 0, stream>>>(xb, wqkT, qn, kn, nullptr, qs, ks);
  // V^T = Wv^T @ x^T
  gemm_k<1><<<dim3(256, 8), 256, 0, stream>>>(wvT, xb, vT, nullptr, nullptr, nullptr, nullptr);
  // attention (overwrites xb with [B,L,D] bf16 attention output)
  attn_k<<<8192, 256, 0, stream>>>(qn, kn, vT, rkb, rvTb, ridx, xb);
  // final projection -> fp32 out
  gemm_k<2><<<dim3(8, 256), 256, 0, stream>>>(xb, woT, nullptr, nullptr, out, nullptr, nullptr);
}

// Round 4
// 955.586 us; speedup vs baseline: 1.0868x; 1.0109x over previous
//
#include <hip/hip_runtime.h>
#include <stdint.h>

typedef unsigned short u16;
typedef __attribute__((ext_vector_type(8))) short s16x8;   // 8 x bf16 (4 VGPRs)
typedef __attribute__((ext_vector_type(4))) float f32x4;

#define DEV static __device__ __forceinline__

#define MFMA16(a, b, c) __builtin_amdgcn_mfma_f32_16x16x32_bf16((a), (b), (c), 0, 0, 0)

// fp32 -> bf16 round-to-nearest-even
DEV u16 f2b(float f) {
  unsigned u = __float_as_uint(f);
  unsigned r = (u + 0x7fffu + ((u >> 16) & 1u)) >> 16;
  return (u16)r;
}
DEV float b2f(u16 u) { return __uint_as_float(((unsigned)u) << 16); }

typedef const __attribute__((address_space(1))) unsigned int* as1p;
typedef __attribute__((address_space(3))) unsigned int* as3p;

// async global->LDS, 16B per lane; lds base must be wave-uniform (HW adds lane*16)
DEV void gload16(const void* g, void* l) {
  __builtin_amdgcn_global_load_lds((as1p)(uintptr_t)g, (as3p)(unsigned)(uintptr_t)l, 16, 0, 0);
}

// packed bf16x2 LDS atomic add (ds_pk_add_bf16)
DEV void ldsPkAddBf16(void* ldsPtr, unsigned packed) {
  unsigned addr = (unsigned)(uintptr_t)ldsPtr;
  asm volatile("ds_pk_add_bf16 %0, %1" : : "v"(addr), "v"(packed) : "memory");
}

// ---------------------------------------------------------------------------
// prep kernels
// ---------------------------------------------------------------------------
__global__ void conv_x_k(const float* __restrict__ x, u16* __restrict__ xb) {
  const int n8 = 32768 * 1024 / 8;
  int i = blockIdx.x * 256 + threadIdx.x;     // 8 floats per thread
  int stride = gridDim.x * 256;
  for (; i < n8; i += stride) {
    const float4* p = (const float4*)x + (size_t)i * 2;
    float4 a = p[0], c = p[1];
    union { s16x8 v; u16 u[8]; } o;
    o.u[0] = f2b(a.x); o.u[1] = f2b(a.y); o.u[2] = f2b(a.z); o.u[3] = f2b(a.w);
    o.u[4] = f2b(c.x); o.u[5] = f2b(c.y); o.u[6] = f2b(c.z); o.u[7] = f2b(c.w);
    *(s16x8*)(xb + (size_t)i * 8) = o.v;
  }
}

// transpose 1024x1024 f32 -> bf16 B^T layouts for all four weights
__global__ void transp_w_k(const float* __restrict__ Wq, const float* __restrict__ Wk,
                           const float* __restrict__ Wv, const float* __restrict__ Wo,
                           u16* __restrict__ wqkT, u16* __restrict__ wvT, u16* __restrict__ woT) {
  const int z = blockIdx.z;
  const float* src = z == 0 ? Wq : z == 1 ? Wk : z == 2 ? Wv : Wo;
  u16* dst = z == 0 ? wqkT : z == 1 ? (wqkT + 1024 * 1024) : z == 2 ? wvT : woT;
  __shared__ u16 t[64][72];
  const int kb = blockIdx.y * 64, nb = blockIdx.x * 64;
  const int tid = threadIdx.x;
  const int c = tid & 63, r0 = tid >> 6;
  #pragma unroll
  for (int s = 0; s < 16; ++s) {
    int r = r0 * 16 + s;
    t[r][c] = f2b(src[(size_t)(kb + r) * 1024 + nb + c]);
  }
  __syncthreads();
  #pragma unroll
  for (int s = 0; s < 16; ++s) {
    int n = r0 * 16 + s;
    dst[(size_t)(nb + n) * 1024 + kb + c] = t[c][n];   // out[n][k] = in[k][n]
  }
}

// rel_k -> bf16 [240][64] (zero pad t>=225); rel_v -> bf16 transposed [64][256] (zero pad)
__global__ void prep_rel_k(const float* __restrict__ rk, const float* __restrict__ rv,
                           u16* __restrict__ rkb, u16* __restrict__ rvT) {
  int i = blockIdx.x * 256 + threadIdx.x;
  if (i < 240 * 64) {
    int tt = i >> 6, d = i & 63;
    rkb[i] = (tt < 225) ? f2b(rk[tt * 64 + d]) : (u16)0;
  }
  if (i < 64 * 256) {
    int d = i >> 8, tt = i & 255;
    rvT[i] = (tt < 225) ? f2b(rv[tt * 64 + d]) : (u16)0;
  }
}

// ---------------------------------------------------------------------------
// 128x128x(K=1024) bf16 MFMA GEMM, BK=32, 4 waves (2x2), 4x4 16x16x32 frags/wave
// ---------------------------------------------------------------------------
template <int EPI>
__global__ __launch_bounds__(256, 2)
void gemm_k(const u16* __restrict__ A, const u16* __restrict__ BT,
            u16* __restrict__ o16a, u16* __restrict__ o16b,
            float* __restrict__ oF,
            const float* __restrict__ qsc, const float* __restrict__ ksc) {
  __shared__ u16 smA[2][128 * 32];
  __shared__ u16 smB[2][128 * 32];
  const int tid = threadIdx.x;
  const int w = tid >> 6, l = tid & 63;
  const int lc = l & 15, l4 = l >> 4;
  // bijective XCD swizzle (nwg % 8 == 0 for all our grids)
  const int nwg = gridDim.x * gridDim.y;
  const int orig = blockIdx.y * gridDim.x + blockIdx.x;
  const int wg = ((orig & 7) * (nwg >> 3)) + (orig >> 3);
  const int bx = wg % gridDim.x, by = wg / gridDim.x;
  const int m0 = by * 128, n0 = bx * 128;
  const int wm = (w >> 1) * 64, wn = (w & 1) * 64;

  f32x4 acc[4][4];
  #pragma unroll
  for (int i = 0; i < 4; ++i)
    #pragma unroll
    for (int j = 0; j < 4; ++j) acc[i][j] = (f32x4){0.f, 0.f, 0.f, 0.f};

  // staging source mapping (XOR swizzle on byte bits [5:4] by row: x = (row^(row>>2))&3)
  int srcRow[2], srcCol[2];
  #pragma unroll
  for (int s = 0; s < 2; ++s) {
    int p = w * 2048 + s * 1024 + l * 16;           // physical LDS byte
    int row = p >> 6;                                // 64B per row (BK=32 bf16)
    int lb = p ^ (((row ^ (row >> 2)) & 3) << 4);    // logical byte
    srcRow[s] = row;
    srcCol[s] = (lb & 63) >> 1;                      // element offset in k-tile
  }

  auto stage = [&](int buf, int kt) {
    #pragma unroll
    for (int s = 0; s < 2; ++s) {
      int base = w * 2048 + s * 1024;                // wave-uniform LDS byte base
      const u16* ga = A + (size_t)(m0 + srcRow[s]) * 1024 + kt * 32 + srcCol[s];
      gload16(ga, (char*)&smA[buf][0] + base);
      const u16* gb = BT + (size_t)(n0 + srcRow[s]) * 1024 + kt * 32 + srcCol[s];
      gload16(gb, (char*)&smB[buf][0] + base);
    }
  };
  auto fragA = [&](int buf, int mf) -> s16x8 {
    int row = wm + mf * 16 + lc;
    int p = (row << 6) + (l4 << 4);
    p ^= ((row ^ (row >> 2)) & 3) << 4;
    return *(const s16x8*)((const char*)&smA[buf][0] + p);
  };
  auto fragB = [&](int buf, int nf) -> s16x8 {
    int row = wn + nf * 16 + lc;
    int p = (row << 6) + (l4 << 4);
    p ^= ((row ^ (row >> 2)) & 3) << 4;
    return *(const s16x8*)((const char*)&smB[buf][0] + p);
  };

  stage(0, 0);
  __syncthreads();
  #pragma unroll 2
  for (int kt = 0; kt < 32; ++kt) {
    int cur = kt & 1;
    if (kt + 1 < 32) stage(cur ^ 1, kt + 1);
    s16x8 af[4], bf[4];
    #pragma unroll
    for (int i = 0; i < 4; ++i) { af[i] = fragA(cur, i); bf[i] = fragB(cur, i); }
    #pragma unroll
    for (int mf = 0; mf < 4; ++mf)
      #pragma unroll
      for (int nf = 0; nf < 4; ++nf)
        acc[mf][nf] = MFMA16(af[mf], bf[nf], acc[mf][nf]);
    __syncthreads();
  }

  // epilogue; C layout: col = lane&15 (+16*nf), row = (lane>>4)*4 + reg (+16*mf)
  if constexpr (EPI == 2) {
    #pragma unroll
    for (int mf = 0; mf < 4; ++mf)
      #pragma unroll
      for (int r = 0; r < 4; ++r) {
        int gm = m0 + wm + mf * 16 + l4 * 4 + r;
        #pragma unroll
        for (int nf = 0; nf < 4; ++nf) {
          int gn = n0 + wn + nf * 16 + lc;
          oF[(size_t)gm * 1024 + gn] = acc[mf][nf][r];
        }
      }
  } else if constexpr (EPI == 1) {
    #pragma unroll
    for (int mf = 0; mf < 4; ++mf)
      #pragma unroll
      for (int r = 0; r < 4; ++r) {
        int gm = m0 + wm + mf * 16 + l4 * 4 + r;       // h*64+d
        #pragma unroll
        for (int nf = 0; nf < 4; ++nf) {
          int gn = n0 + wn + nf * 16 + lc;             // b*64+l
          size_t addr = (((size_t)(gn >> 6) * 16 + (gm >> 6)) * 64 + (gm & 63)) * 64 + (gn & 63);
          o16a[addr] = f2b(acc[mf][nf][r]);
        }
      }
  } else {
    int nw0 = n0 + wn;                                  // wave = exactly one head (64 cols)
    bool isq = nw0 < 1024;
    const float* sc = isq ? qsc : ksc;
    u16* dst = isq ? o16a : o16b;
    int h = (nw0 & 1023) >> 6;
    float scv[4];
    #pragma unroll
    for (int nf = 0; nf < 4; ++nf) scv[nf] = sc[nf * 16 + lc];
    #pragma unroll
    for (int mf = 0; mf < 4; ++mf)
      #pragma unroll
      for (int r = 0; r < 4; ++r) {
        float ss = 0.f;
        #pragma unroll
        for (int nf = 0; nf < 4; ++nf) ss += acc[mf][nf][r] * acc[mf][nf][r];
        #pragma unroll
        for (int mask = 1; mask < 16; mask <<= 1) ss += __shfl_xor(ss, mask, 64);
        float rinv = rsqrtf(ss * 0.015625f + 1e-6f);    // 1/sqrt(mean+eps)
        int gm = m0 + wm + mf * 16 + l4 * 4 + r;
        size_t base = (((size_t)(gm >> 6) * 16 + h) * 64 + (gm & 63)) * 64;
        #pragma unroll
        for (int nf = 0; nf < 4; ++nf)
          dst[base + nf * 16 + lc] = f2b(acc[mf][nf][r] * rinv * scv[nf]);
      }
  }
}

// ---------------------------------------------------------------------------
// attention v3: one block (4 waves) per (b,h); wave w owns query rows [16w,16w+16)
// K/V tiles staged via async global_load_lds (swizzled source, linear dest);
// rel_k frags bulk-loaded before the first barrier (one latency drain);
// rel_v frags bulk-loaded two barriers before use. VGPR-generous (256,2).
// ---------------------------------------------------------------------------
// RW swizzled byte address of bf16 element (row, t): 16B slots XORed by row&7
DEV int rwByte(int row, int t) {
  return row * 512 + ((((t >> 3) ^ (row & 7)) << 4)) + ((t & 7) * 2);
}

__global__ __launch_bounds__(256, 2)
void attn_k(const u16* __restrict__ qn, const u16* __restrict__ kn,
            const u16* __restrict__ vT, const u16* __restrict__ rkb,
            const u16* __restrict__ rvT, const int* __restrict__ ridx,
            u16* __restrict__ ao) {
  __shared__ u16 Ksm[64 * 64];   // 8 KB, row=t, 8 slots/row, slot^=(row&7)
  __shared__ u16 Vsm[64 * 64];   // 8 KB, row=d, same swizzle
  __shared__ u16 RW[64 * 256];   // 32 KB: R table, then scatter-W
  __shared__ u16 Pl[64 * 72];    // 9 KB: P staging for PV A-frags
  const int bid = blockIdx.x;
  const int b = bid >> 4, h = bid & 15;
  const int tid = threadIdx.x;
  const int w = tid >> 6, l = tid & 63;
  const int lc = l & 15, l4 = l >> 4;
  const int i0 = w * 16;
  const size_t hb = (size_t)(b * 16 + h) * 4096;
  const u16* qh = qn + hb;
  const u16* kh = kn + hb;
  const u16* vh = vT + hb;

  // ---- async stage K and V (zero VGPR cost, in flight immediately)
  #pragma unroll
  for (int s = 0; s < 2; ++s) {
    int p = w * 2048 + s * 1024 + l * 16;            // LDS byte this lane fills
    int t = p >> 7;                                   // row (128B rows)
    int sl = ((p >> 4) & 7) ^ (t & 7);                // logical slot (XOR involution)
    int e = t * 64 + sl * 8;                          // element offset in 64x64 tile
    gload16(kh + e, (char*)Ksm + w * 2048 + s * 1024);
    gload16(vh + e, (char*)Vsm + w * 2048 + s * 1024);
  }

  // ---- register loads issued before the barrier: ridx, q, ALL rel_k frags
  int ts[4][4];
  #pragma unroll
  for (int q = 0; q < 4; ++q) {
    int row = i0 + l4 * 4 + q;
    #pragma unroll
    for (int nf = 0; nf < 4; ++nf) ts[nf][q] = ridx[row * 64 + nf * 16 + lc];
  }
  s16x8 aq0 = *(const s16x8*)(qh + (i0 + lc) * 64 + l4 * 8);
  s16x8 aq1 = *(const s16x8*)(qh + (i0 + lc) * 64 + 32 + l4 * 8);

  f32x4 accC[4];
  #pragma unroll
  for (int nf = 0; nf < 4; ++nf) accC[nf] = (f32x4){0.f, 0.f, 0.f, 0.f};

  {
    s16x8 rb0[15], rb1[15];
    #pragma unroll
    for (int u = 0; u < 15; ++u) {
      rb0[u] = *(const s16x8*)(rkb + (u * 16 + lc) * 64 + l4 * 8);
      rb1[u] = *(const s16x8*)(rkb + (u * 16 + lc) * 64 + 32 + l4 * 8);
    }
    __syncthreads();                              // S1: K/V in LDS (drains all VMEM)

    // P1: content = Q @ K^T from LDS
    #pragma unroll
    for (int nf = 0; nf < 4; ++nf) {
      int row = nf * 16 + lc;
      s16x8 k0 = *(const s16x8*)((const char*)Ksm + row * 128 + (((0 + l4) ^ (row & 7)) << 4));
      s16x8 k1 = *(const s16x8*)((const char*)Ksm + row * 128 + (((4 + l4) ^ (row & 7)) << 4));
      accC[nf] = MFMA16(aq0, k0, accC[nf]);
      accC[nf] = MFMA16(aq1, k1, accC[nf]);
    }

    // P2: R[i,t] = q_i . rel_k[t] -> RW (bf16, swizzled)
    #pragma unroll
    for (int u = 0; u < 15; ++u) {
      f32x4 rr = (f32x4){0.f, 0.f, 0.f, 0.f};
      rr = MFMA16(aq0, rb0[u], rr);
      rr = MFMA16(aq1, rb1[u], rr);
      int t = u * 16 + lc;
      #pragma unroll
      for (int q = 0; q < 4; ++q) {
        int row = i0 + l4 * 4 + q;
        RW[rwByte(row, t) >> 1] = f2b(rr[q]);
      }
    }
  }
  __syncthreads();                               // S2: R visible

  // P3: gather rel, scores, 16-lane-group softmax; stash P (bf16)
  float ev[4][4];
  float linv[4];
  #pragma unroll
  for (int q = 0; q < 4; ++q) {
    int row = i0 + l4 * 4 + q;
    float mx = -1e30f;
    #pragma unroll
    for (int nf = 0; nf < 4; ++nf) {
      float r = b2f(RW[rwByte(row, ts[nf][q]) >> 1]);
      float s = (accC[nf][q] + r) * 0.125f;
      ev[nf][q] = s;
      mx = fmaxf(mx, s);
    }
    #pragma unroll
    for (int mask = 1; mask < 16; mask <<= 1) mx = fmaxf(mx, __shfl_xor(mx, mask, 64));
    float sum = 0.f;
    #pragma unroll
    for (int nf = 0; nf < 4; ++nf) { float e = __expf(ev[nf][q] - mx); ev[nf][q] = e; sum += e; }
    #pragma unroll
    for (int mask = 1; mask < 16; mask <<= 1) sum += __shfl_xor(sum, mask, 64);
    linv[q] = 1.f / sum;
    #pragma unroll
    for (int nf = 0; nf < 4; ++nf) Pl[row * 72 + nf * 16 + lc] = f2b(ev[nf][q]);
  }
  __syncthreads();                               // S3: RW reads done; Pl visible

  // P4: bulk-load ALL rel_v frags (consumed in P6, two barriers away),
  //     zero W, and run PV MFMAs (V from LDS)
  s16x8 rvf[8][4];
  #pragma unroll
  for (int ks = 0; ks < 8; ++ks)
    #pragma unroll
    for (int nf = 0; nf < 4; ++nf)
      rvf[ks][nf] = *(const s16x8*)(rvT + (nf * 16 + lc) * 256 + ks * 32 + l4 * 8);
  {
    s16x8 z;
    #pragma unroll
    for (int j = 0; j < 8; ++j) z[j] = 0;
    #pragma unroll
    for (int zz = 0; zz < 8; ++zz) ((s16x8*)RW)[zz * 256 + tid] = z;
  }
  f32x4 accO[4];
  #pragma unroll
  for (int nf = 0; nf < 4; ++nf) accO[nf] = (f32x4){0.f, 0.f, 0.f, 0.f};
  s16x8 pa0 = *(const s16x8*)(&Pl[(i0 + lc) * 72 + l4 * 8]);
  s16x8 pa1 = *(const s16x8*)(&Pl[(i0 + lc) * 72 + 32 + l4 * 8]);
  #pragma unroll
  for (int nf = 0; nf < 4; ++nf) {
    int row = nf * 16 + lc;
    s16x8 v0 = *(const s16x8*)((const char*)Vsm + row * 128 + (((0 + l4) ^ (row & 7)) << 4));
    s16x8 v1 = *(const s16x8*)((const char*)Vsm + row * 128 + (((4 + l4) ^ (row & 7)) << 4));
    accO[nf] = MFMA16(pa0, v0, accO[nf]);
    accO[nf] = MFMA16(pa1, v1, accO[nf]);
  }
  __syncthreads();                               // S4: W zeroed

  // P5: scatter unnormalized probs via packed-bf16 LDS atomic
  #pragma unroll
  for (int q = 0; q < 4; ++q)
    #pragma unroll
    for (int nf = 0; nf < 4; ++nf) {
      int row = i0 + l4 * 4 + q;
      int t = ts[nf][q];
      int byte = row * 512 + ((((t >> 3) ^ (row & 7)) << 4)) + ((t & 6) * 2);
      unsigned pk = ((unsigned)f2b(ev[nf][q])) << ((t & 1) * 16);
      ldsPkAddBf16((char*)RW + byte, pk);
    }
  asm volatile("s_waitcnt lgkmcnt(0)" ::: "memory");
  __syncthreads();                               // S5: W complete

  // P6: accO += W @ rel_v  (W A-frags from swizzled LDS; rel_v from regs)
  #pragma unroll
  for (int ks = 0; ks < 8; ++ks) {
    int row = i0 + lc;
    s16x8 wa = *(const s16x8*)((const char*)RW + row * 512 + ((((ks * 4 + l4) ^ (row & 7))) << 4));
    #pragma unroll
    for (int nf = 0; nf < 4; ++nf)
      accO[nf] = MFMA16(wa, rvf[ks][nf], accO[nf]);
  }

  // P7: write [B,L,H*dk] bf16
  #pragma unroll
  for (int q = 0; q < 4; ++q) {
    int row = i0 + l4 * 4 + q;
    #pragma unroll
    for (int nf = 0; nf < 4; ++nf) {
      int d = nf * 16 + lc;
      ao[((size_t)(b * 64 + row)) * 1024 + h * 64 + d] = f2b(accO[nf][q] * linv[q]);
    }
  }
}

// ---------------------------------------------------------------------------
extern "C" void kernel_launch(void* const* d_in, const int* in_sizes, int n_in,
                              void* d_out, int out_size, void* d_ws, size_t ws_size,
                              hipStream_t stream) {
  (void)in_sizes; (void)n_in; (void)out_size; (void)ws_size;
  const float* x  = (const float*)d_in[0];
  const int* ridx = (const int*)d_in[1];   // harness delivers integer inputs as int32
  const float* Wq = (const float*)d_in[2];
  const float* Wk = (const float*)d_in[3];
  const float* Wv = (const float*)d_in[4];
  const float* Wo = (const float*)d_in[5];
  const float* qs = (const float*)d_in[6];
  const float* ks = (const float*)d_in[7];
  const float* rk = (const float*)d_in[8];
  const float* rv = (const float*)d_in[9];
  float* out = (float*)d_out;

  char* ws = (char*)d_ws;
  const size_t SZ = 32768ull * 1024 * 2;            // 64 MiB (bf16 activation)
  u16* xb   = (u16*)(ws);                           // x bf16; later reused as attn out
  u16* qn   = (u16*)(ws + SZ);                      // Q rmsnorm'd [B,H,L,dk]
  u16* kn   = (u16*)(ws + 2 * SZ);                  // K rmsnorm'd [B,H,L,dk]
  u16* vT   = (u16*)(ws + 3 * SZ);                  // V^T [B,H,dk,L]
  u16* wqkT = (u16*)(ws + 4 * SZ);                  // [2048][1024]
  u16* wvT  = (u16*)(ws + 4 * SZ + 4194304);        // [1024][1024]
  u16* woT  = (u16*)(ws + 4 * SZ + 6291456);        // [1024][1024]
  u16* rkb  = (u16*)(ws + 4 * SZ + 8388608);        // [240][64]
  u16* rvTb = (u16*)(ws + 4 * SZ + 8388608 + 30720);// [64][256]

  conv_x_k<<<2048, 256, 0, stream>>>(x, xb);
  transp_w_k<<<dim3(16, 16, 4), 256, 0, stream>>>(Wq, Wk, Wv, Wo, wqkT, wvT, woT);
  prep_rel_k<<<64, 256, 0, stream>>>(rk, rv, rkb, rvTb);
  // Q,K projection + fused RMSNorm
  gemm_k<0><<<dim3(16, 256), 256, 0, stream>>>(xb, wqkT, qn, kn, nullptr, qs, ks);
  // V^T = Wv^T @ x^T
  gemm_k<1><<<dim3(256, 8), 256, 0, stream>>>(wvT, xb, vT, nullptr, nullptr, nullptr, nullptr);
  // attention (overwrites xb with [B,L,D] bf16 attention output)
  attn_k<<<8192, 256, 0, stream>>>(qn, kn, vT, rkb, rvTb, ridx, xb);
  // final projection -> fp32 out
  gemm_k<2><<<dim3(8, 256), 256, 0, stream>>>(xb, woT, nullptr, nullptr, out, nullptr, nullptr);
}

// Round 5
// 894.291 us; speedup vs baseline: 1.1613x; 1.0685x over previous
//
#include <hip/hip_runtime.h>
#include <stdint.h>

typedef unsigned short u16;
typedef __attribute__((ext_vector_type(8))) short s16x8;   // 8 x bf16 (4 VGPRs)
typedef __attribute__((ext_vector_type(4))) float f32x4;

#define DEV static __device__ __forceinline__

#define MFMA16(a, b, c) __builtin_amdgcn_mfma_f32_16x16x32_bf16((a), (b), (c), 0, 0, 0)

// fp32 -> bf16 round-to-nearest-even
DEV u16 f2b(float f) {
  unsigned u = __float_as_uint(f);
  unsigned r = (u + 0x7fffu + ((u >> 16) & 1u)) >> 16;
  return (u16)r;
}
DEV float b2f(u16 u) { return __uint_as_float(((unsigned)u) << 16); }

typedef const __attribute__((address_space(1))) unsigned int* as1p;
typedef __attribute__((address_space(3))) unsigned int* as3p;

// async global->LDS, 16B per lane; lds base must be wave-uniform (HW adds lane*16)
DEV void gload16(const void* g, void* l) {
  __builtin_amdgcn_global_load_lds((as1p)(uintptr_t)g, (as3p)(unsigned)(uintptr_t)l, 16, 0, 0);
}

// packed bf16x2 LDS atomic add (ds_pk_add_bf16)
DEV void ldsPkAddBf16(void* ldsPtr, unsigned packed) {
  unsigned addr = (unsigned)(uintptr_t)ldsPtr;
  asm volatile("ds_pk_add_bf16 %0, %1" : : "v"(addr), "v"(packed) : "memory");
}

DEV void waitLds() {
  asm volatile("s_waitcnt lgkmcnt(0)" ::: "memory");
  __builtin_amdgcn_sched_barrier(0);   // rule #18: stop hoisting past the wait
}

// ---------------------------------------------------------------------------
// prep kernels
// ---------------------------------------------------------------------------
__global__ void conv_x_k(const float* __restrict__ x, u16* __restrict__ xb) {
  const int n8 = 32768 * 1024 / 8;
  int i = blockIdx.x * 256 + threadIdx.x;     // 8 floats per thread
  int stride = gridDim.x * 256;
  for (; i < n8; i += stride) {
    const float4* p = (const float4*)x + (size_t)i * 2;
    float4 a = p[0], c = p[1];
    union { s16x8 v; u16 u[8]; } o;
    o.u[0] = f2b(a.x); o.u[1] = f2b(a.y); o.u[2] = f2b(a.z); o.u[3] = f2b(a.w);
    o.u[4] = f2b(c.x); o.u[5] = f2b(c.y); o.u[6] = f2b(c.z); o.u[7] = f2b(c.w);
    *(s16x8*)(xb + (size_t)i * 8) = o.v;
  }
}

// transpose 1024x1024 f32 -> bf16 B^T layouts for all four weights
__global__ void transp_w_k(const float* __restrict__ Wq, const float* __restrict__ Wk,
                           const float* __restrict__ Wv, const float* __restrict__ Wo,
                           u16* __restrict__ wqkT, u16* __restrict__ wvT, u16* __restrict__ woT) {
  const int z = blockIdx.z;
  const float* src = z == 0 ? Wq : z == 1 ? Wk : z == 2 ? Wv : Wo;
  u16* dst = z == 0 ? wqkT : z == 1 ? (wqkT + 1024 * 1024) : z == 2 ? wvT : woT;
  __shared__ u16 t[64][72];
  const int kb = blockIdx.y * 64, nb = blockIdx.x * 64;
  const int tid = threadIdx.x;
  const int c = tid & 63, r0 = tid >> 6;
  #pragma unroll
  for (int s = 0; s < 16; ++s) {
    int r = r0 * 16 + s;
    t[r][c] = f2b(src[(size_t)(kb + r) * 1024 + nb + c]);
  }
  __syncthreads();
  #pragma unroll
  for (int s = 0; s < 16; ++s) {
    int n = r0 * 16 + s;
    dst[(size_t)(nb + n) * 1024 + kb + c] = t[c][n];   // out[n][k] = in[k][n]
  }
}

// rel_k -> bf16 [240][64] (zero pad t>=225); rel_v -> bf16 transposed [64][256] (zero pad)
__global__ void prep_rel_k(const float* __restrict__ rk, const float* __restrict__ rv,
                           u16* __restrict__ rkb, u16* __restrict__ rvT) {
  int i = blockIdx.x * 256 + threadIdx.x;
  if (i < 240 * 64) {
    int tt = i >> 6, d = i & 63;
    rkb[i] = (tt < 225) ? f2b(rk[tt * 64 + d]) : (u16)0;
  }
  if (i < 64 * 256) {
    int d = i >> 8, tt = i & 255;
    rvT[i] = (tt < 225) ? f2b(rv[tt * 64 + d]) : (u16)0;
  }
}

// ---------------------------------------------------------------------------
// 128x128x(K=1024) bf16 MFMA GEMM, BK=32, 4 waves (2x2), 4x4 16x16x32 frags/wave
// ---------------------------------------------------------------------------
template <int EPI>
__global__ __launch_bounds__(256, 2)
void gemm_k(const u16* __restrict__ A, const u16* __restrict__ BT,
            u16* __restrict__ o16a, u16* __restrict__ o16b,
            float* __restrict__ oF,
            const float* __restrict__ qsc, const float* __restrict__ ksc) {
  __shared__ u16 smA[2][128 * 32];
  __shared__ u16 smB[2][128 * 32];
  const int tid = threadIdx.x;
  const int w = tid >> 6, l = tid & 63;
  const int lc = l & 15, l4 = l >> 4;
  // bijective XCD swizzle (nwg % 8 == 0 for all our grids)
  const int nwg = gridDim.x * gridDim.y;
  const int orig = blockIdx.y * gridDim.x + blockIdx.x;
  const int wg = ((orig & 7) * (nwg >> 3)) + (orig >> 3);
  const int bx = wg % gridDim.x, by = wg / gridDim.x;
  const int m0 = by * 128, n0 = bx * 128;
  const int wm = (w >> 1) * 64, wn = (w & 1) * 64;

  f32x4 acc[4][4];
  #pragma unroll
  for (int i = 0; i < 4; ++i)
    #pragma unroll
    for (int j = 0; j < 4; ++j) acc[i][j] = (f32x4){0.f, 0.f, 0.f, 0.f};

  // staging source mapping (XOR swizzle on byte bits [5:4] by row: x = (row^(row>>2))&3)
  int srcRow[2], srcCol[2];
  #pragma unroll
  for (int s = 0; s < 2; ++s) {
    int p = w * 2048 + s * 1024 + l * 16;           // physical LDS byte
    int row = p >> 6;                                // 64B per row (BK=32 bf16)
    int lb = p ^ (((row ^ (row >> 2)) & 3) << 4);    // logical byte
    srcRow[s] = row;
    srcCol[s] = (lb & 63) >> 1;                      // element offset in k-tile
  }

  auto stage = [&](int buf, int kt) {
    #pragma unroll
    for (int s = 0; s < 2; ++s) {
      int base = w * 2048 + s * 1024;                // wave-uniform LDS byte base
      const u16* ga = A + (size_t)(m0 + srcRow[s]) * 1024 + kt * 32 + srcCol[s];
      gload16(ga, (char*)&smA[buf][0] + base);
      const u16* gb = BT + (size_t)(n0 + srcRow[s]) * 1024 + kt * 32 + srcCol[s];
      gload16(gb, (char*)&smB[buf][0] + base);
    }
  };
  auto fragA = [&](int buf, int mf) -> s16x8 {
    int row = wm + mf * 16 + lc;
    int p = (row << 6) + (l4 << 4);
    p ^= ((row ^ (row >> 2)) & 3) << 4;
    return *(const s16x8*)((const char*)&smA[buf][0] + p);
  };
  auto fragB = [&](int buf, int nf) -> s16x8 {
    int row = wn + nf * 16 + lc;
    int p = (row << 6) + (l4 << 4);
    p ^= ((row ^ (row >> 2)) & 3) << 4;
    return *(const s16x8*)((const char*)&smB[buf][0] + p);
  };

  stage(0, 0);
  __syncthreads();
  #pragma unroll 2
  for (int kt = 0; kt < 32; ++kt) {
    int cur = kt & 1;
    if (kt + 1 < 32) stage(cur ^ 1, kt + 1);
    s16x8 af[4], bf[4];
    #pragma unroll
    for (int i = 0; i < 4; ++i) { af[i] = fragA(cur, i); bf[i] = fragB(cur, i); }
    #pragma unroll
    for (int mf = 0; mf < 4; ++mf)
      #pragma unroll
      for (int nf = 0; nf < 4; ++nf)
        acc[mf][nf] = MFMA16(af[mf], bf[nf], acc[mf][nf]);
    __syncthreads();
  }

  // epilogue; C layout: col = lane&15 (+16*nf), row = (lane>>4)*4 + reg (+16*mf)
  if constexpr (EPI == 2) {
    #pragma unroll
    for (int mf = 0; mf < 4; ++mf)
      #pragma unroll
      for (int r = 0; r < 4; ++r) {
        int gm = m0 + wm + mf * 16 + l4 * 4 + r;
        #pragma unroll
        for (int nf = 0; nf < 4; ++nf) {
          int gn = n0 + wn + nf * 16 + lc;
          oF[(size_t)gm * 1024 + gn] = acc[mf][nf][r];
        }
      }
  } else if constexpr (EPI == 1) {
    #pragma unroll
    for (int mf = 0; mf < 4; ++mf)
      #pragma unroll
      for (int r = 0; r < 4; ++r) {
        int gm = m0 + wm + mf * 16 + l4 * 4 + r;       // h*64+d
        #pragma unroll
        for (int nf = 0; nf < 4; ++nf) {
          int gn = n0 + wn + nf * 16 + lc;             // b*64+l
          size_t addr = (((size_t)(gn >> 6) * 16 + (gm >> 6)) * 64 + (gm & 63)) * 64 + (gn & 63);
          o16a[addr] = f2b(acc[mf][nf][r]);
        }
      }
  } else {
    int nw0 = n0 + wn;                                  // wave = exactly one head (64 cols)
    bool isq = nw0 < 1024;
    const float* sc = isq ? qsc : ksc;
    u16* dst = isq ? o16a : o16b;
    int h = (nw0 & 1023) >> 6;
    float scv[4];
    #pragma unroll
    for (int nf = 0; nf < 4; ++nf) scv[nf] = sc[nf * 16 + lc];
    #pragma unroll
    for (int mf = 0; mf < 4; ++mf)
      #pragma unroll
      for (int r = 0; r < 4; ++r) {
        float ss = 0.f;
        #pragma unroll
        for (int nf = 0; nf < 4; ++nf) ss += acc[mf][nf][r] * acc[mf][nf][r];
        #pragma unroll
        for (int mask = 1; mask < 16; mask <<= 1) ss += __shfl_xor(ss, mask, 64);
        float rinv = rsqrtf(ss * 0.015625f + 1e-6f);    // 1/sqrt(mean+eps)
        int gm = m0 + wm + mf * 16 + l4 * 4 + r;
        size_t base = (((size_t)(gm >> 6) * 16 + h) * 64 + (gm & 63)) * 64;
        #pragma unroll
        for (int nf = 0; nf < 4; ++nf)
          dst[base + nf * 16 + lc] = f2b(acc[mf][nf][r] * rinv * scv[nf]);
      }
  }
}

// ---------------------------------------------------------------------------
// attention v4: ONE WAVE PER BLOCK, one (b, h, 16-row-group) each, NO barriers.
// All LDS (RW scatter table + Pl) is wave-private; ordering via lgkmcnt only.
// 32768 blocks x 64 threads; LDS 10.5 KB -> high occupancy of independent waves.
// ---------------------------------------------------------------------------
// swizzled byte address of bf16 element (local row, t): 16B slots XORed by row&7
DEV int rwByte(int row, int t) {
  return row * 512 + ((((t >> 3) ^ (row & 7)) << 4)) + ((t & 7) * 2);
}

__global__ __launch_bounds__(64, 3)
void attn_k(const u16* __restrict__ qn, const u16* __restrict__ kn,
            const u16* __restrict__ vT, const u16* __restrict__ rkb,
            const u16* __restrict__ rvT, const int* __restrict__ ridx,
            u16* __restrict__ ao) {
  __shared__ u16 RW[16 * 256];   // 8 KB: R table, then scatter-W (this wave's rows)
  __shared__ u16 Pl[16 * 72];    // 2.25 KB: P staging for PV A-frags
  // XCD-chunked bijective swizzle (32768 % 8 == 0): contiguous range per XCD
  const int bid0 = blockIdx.x;
  const int bid = (bid0 & 7) * 4096 + (bid0 >> 3);
  const int rg = bid & 3, h = (bid >> 2) & 15, b = bid >> 6;
  const int i0 = rg * 16;                  // global query-row base
  const int l = threadIdx.x;               // 0..63 (one wave)
  const int lc = l & 15, l4 = l >> 4;
  const size_t hb = (size_t)(b * 16 + h) * 4096;
  const u16* qh = qn + hb;
  const u16* kh = kn + hb;
  const u16* vh = vT + hb;

  // Q frags (A-operand, rows i0..i0+15)
  s16x8 aq0 = *(const s16x8*)(qh + (i0 + lc) * 64 + l4 * 8);
  s16x8 aq1 = *(const s16x8*)(qh + (i0 + lc) * 64 + 32 + l4 * 8);

  // P1: content = Q @ K^T (K frags from global; loads hoist/pipeline freely)
  f32x4 accC[4];
  #pragma unroll
  for (int nf = 0; nf < 4; ++nf) accC[nf] = (f32x4){0.f, 0.f, 0.f, 0.f};
  #pragma unroll
  for (int nf = 0; nf < 4; ++nf) {
    s16x8 k0 = *(const s16x8*)(kh + (nf * 16 + lc) * 64 + l4 * 8);
    s16x8 k1 = *(const s16x8*)(kh + (nf * 16 + lc) * 64 + 32 + l4 * 8);
    accC[nf] = MFMA16(aq0, k0, accC[nf]);
    accC[nf] = MFMA16(aq1, k1, accC[nf]);
  }

  // P2: R[r,t] = q_(i0+r) . rel_k[t] -> RW (bf16, swizzled); local rows r=l4*4+q
  #pragma unroll
  for (int u = 0; u < 15; ++u) {
    s16x8 rb0 = *(const s16x8*)(rkb + (u * 16 + lc) * 64 + l4 * 8);
    s16x8 rb1 = *(const s16x8*)(rkb + (u * 16 + lc) * 64 + 32 + l4 * 8);
    f32x4 rr = (f32x4){0.f, 0.f, 0.f, 0.f};
    rr = MFMA16(aq0, rb0, rr);
    rr = MFMA16(aq1, rb1, rr);
    int t = u * 16 + lc;
    #pragma unroll
    for (int q = 0; q < 4; ++q) {
      int r = l4 * 4 + q;
      RW[rwByte(r, t) >> 1] = f2b(rr[q]);
    }
  }
  waitLds();                                   // R writes visible to own reads

  // P3: gather rel, scores, 16-lane-group softmax; stash P (bf16) in Pl
  int ts[4][4];
  #pragma unroll
  for (int q = 0; q < 4; ++q) {
    int grow = i0 + l4 * 4 + q;
    #pragma unroll
    for (int nf = 0; nf < 4; ++nf) ts[nf][q] = ridx[grow * 64 + nf * 16 + lc];
  }
  float ev[4][4];
  float linv[4];
  #pragma unroll
  for (int q = 0; q < 4; ++q) {
    int r = l4 * 4 + q;
    float mx = -1e30f;
    #pragma unroll
    for (int nf = 0; nf < 4; ++nf) {
      float rv = b2f(RW[rwByte(r, ts[nf][q]) >> 1]);
      float s = (accC[nf][q] + rv) * 0.125f;
      ev[nf][q] = s;
      mx = fmaxf(mx, s);
    }
    #pragma unroll
    for (int mask = 1; mask < 16; mask <<= 1) mx = fmaxf(mx, __shfl_xor(mx, mask, 64));
    float sum = 0.f;
    #pragma unroll
    for (int nf = 0; nf < 4; ++nf) { float e = __expf(ev[nf][q] - mx); ev[nf][q] = e; sum += e; }
    #pragma unroll
    for (int mask = 1; mask < 16; mask <<= 1) sum += __shfl_xor(sum, mask, 64);
    linv[q] = 1.f / sum;
    #pragma unroll
    for (int nf = 0; nf < 4; ++nf) Pl[r * 72 + nf * 16 + lc] = f2b(ev[nf][q]);
  }
  waitLds();                                   // Pl visible; R reads complete

  // P4: zero W (own region) + PV MFMAs (V frags from global)
  {
    s16x8 z;
    #pragma unroll
    for (int j = 0; j < 8; ++j) z[j] = 0;
    #pragma unroll
    for (int zz = 0; zz < 8; ++zz) ((s16x8*)RW)[zz * 64 + l] = z;
  }
  s16x8 pa0 = *(const s16x8*)(&Pl[lc * 72 + l4 * 8]);
  s16x8 pa1 = *(const s16x8*)(&Pl[lc * 72 + 32 + l4 * 8]);
  f32x4 accO[4];
  #pragma unroll
  for (int nf = 0; nf < 4; ++nf) accO[nf] = (f32x4){0.f, 0.f, 0.f, 0.f};
  #pragma unroll
  for (int nf = 0; nf < 4; ++nf) {
    s16x8 v0 = *(const s16x8*)(vh + (nf * 16 + lc) * 64 + l4 * 8);
    s16x8 v1 = *(const s16x8*)(vh + (nf * 16 + lc) * 64 + 32 + l4 * 8);
    accO[nf] = MFMA16(pa0, v0, accO[nf]);
    accO[nf] = MFMA16(pa1, v1, accO[nf]);
  }
  waitLds();                                   // zero complete before scatter

  // P5: scatter unnormalized probs via packed-bf16 LDS atomic (own rows)
  #pragma unroll
  for (int q = 0; q < 4; ++q)
    #pragma unroll
    for (int nf = 0; nf < 4; ++nf) {
      int r = l4 * 4 + q;
      int t = ts[nf][q];
      int byte = r * 512 + ((((t >> 3) ^ (r & 7)) << 4)) + ((t & 6) * 2);
      unsigned pk = ((unsigned)f2b(ev[nf][q])) << ((t & 1) * 16);
      ldsPkAddBf16((char*)RW + byte, pk);
    }
  waitLds();                                   // W complete

  // P6: accO += W @ rel_v  (W A-frags from swizzled LDS; rel_v frags from global)
  #pragma unroll
  for (int ks = 0; ks < 8; ++ks) {
    int r = lc;                                // local row
    s16x8 wa = *(const s16x8*)((const char*)RW + r * 512 + ((((ks * 4 + l4) ^ (r & 7))) << 4));
    #pragma unroll
    for (int nf = 0; nf < 4; ++nf) {
      s16x8 rb = *(const s16x8*)(rvT + (nf * 16 + lc) * 256 + ks * 32 + l4 * 8);
      accO[nf] = MFMA16(wa, rb, accO[nf]);
    }
  }

  // P7: write [B,L,H*dk] bf16
  #pragma unroll
  for (int q = 0; q < 4; ++q) {
    int grow = i0 + l4 * 4 + q;
    #pragma unroll
    for (int nf = 0; nf < 4; ++nf) {
      int d = nf * 16 + lc;
      ao[((size_t)(b * 64 + grow)) * 1024 + h * 64 + d] = f2b(accO[nf][q] * linv[q]);
    }
  }
}

// ---------------------------------------------------------------------------
extern "C" void kernel_launch(void* const* d_in, const int* in_sizes, int n_in,
                              void* d_out, int out_size, void* d_ws, size_t ws_size,
                              hipStream_t stream) {
  (void)in_sizes; (void)n_in; (void)out_size; (void)ws_size;
  const float* x  = (const float*)d_in[0];
  const int* ridx = (const int*)d_in[1];   // harness delivers integer inputs as int32
  const float* Wq = (const float*)d_in[2];
  const float* Wk = (const float*)d_in[3];
  const float* Wv = (const float*)d_in[4];
  const float* Wo = (const float*)d_in[5];
  const float* qs = (const float*)d_in[6];
  const float* ks = (const float*)d_in[7];
  const float* rk = (const float*)d_in[8];
  const float* rv = (const float*)d_in[9];
  float* out = (float*)d_out;

  char* ws = (char*)d_ws;
  const size_t SZ = 32768ull * 1024 * 2;            // 64 MiB (bf16 activation)
  u16* xb   = (u16*)(ws);                           // x bf16; later reused as attn out
  u16* qn   = (u16*)(ws + SZ);                      // Q rmsnorm'd [B,H,L,dk]
  u16* kn   = (u16*)(ws + 2 * SZ);                  // K rmsnorm'd [B,H,L,dk]
  u16* vT   = (u16*)(ws + 3 * SZ);                  // V^T [B,H,dk,L]
  u16* wqkT = (u16*)(ws + 4 * SZ);                  // [2048][1024]
  u16* wvT  = (u16*)(ws + 4 * SZ + 4194304);        // [1024][1024]
  u16* woT  = (u16*)(ws + 4 * SZ + 6291456);        // [1024][1024]
  u16* rkb  = (u16*)(ws + 4 * SZ + 8388608);        // [240][64]
  u16* rvTb = (u16*)(ws + 4 * SZ + 8388608 + 30720);// [64][256]

  conv_x_k<<<2048, 256, 0, stream>>>(x, xb);
  transp_w_k<<<dim3(16, 16, 4), 256, 0, stream>>>(Wq, Wk, Wv, Wo, wqkT, wvT, woT);
  prep_rel_k<<<64, 256, 0, stream>>>(rk, rv, rkb, rvTb);
  // Q,K projection + fused RMSNorm
  gemm_k<0><<<dim3(16, 256), 256, 0, stream>>>(xb, wqkT, qn, kn, nullptr, qs, ks);
  // V^T = Wv^T @ x^T
  gemm_k<1><<<dim3(256, 8), 256, 0, stream>>>(wvT, xb, vT, nullptr, nullptr, nullptr, nullptr);
  // attention: one wave per (b, h, 16 rows); overwrites xb with [B,L,D] bf16
  attn_k<<<32768, 64, 0, stream>>>(qn, kn, vT, rkb, rvTb, ridx, xb);
  // final projection -> fp32 out
  gemm_k<2><<<dim3(8, 256), 256, 0, stream>>>(xb, woT, nullptr, nullptr, out, nullptr, nullptr);
}